// Round 1
// baseline (238.043 us; speedup 1.0000x reference)
//
#include <hip/hip_runtime.h>
#include <hip/hip_bf16.h>
#include <math.h>

#define BB 8
#define NN 128
#define HN 256
#define HE 128
#define NH 8
#define DH 32
#define PP 8128
#define BP (BB*PP)   // 65024

typedef __hip_bfloat16 bf16;
typedef __hip_bfloat162 bf162;
typedef __attribute__((ext_vector_type(8))) short bf16x8;
typedef __attribute__((ext_vector_type(4))) float f32x4;

__device__ __forceinline__ float bf2f(bf16 x){ return __bfloat162float(x); }
__device__ __forceinline__ float bfraw2f(short u){
  return __uint_as_float(((unsigned)(unsigned short)u) << 16);
}

__device__ __forceinline__ float wave_sum(float v){
  #pragma unroll
  for (int off=32; off>=1; off>>=1) v += __shfl_xor(v, off, 64);
  return v;
}
__device__ __forceinline__ float g16_sum(float v){
  #pragma unroll
  for (int off=8; off>=1; off>>=1) v += __shfl_xor(v, off, 16);
  return v;
}

// triu pair index for N=128, i<j: p = i*(255-i)/2 + (j-i-1)
__device__ __forceinline__ int pair_idx(int a, int c){
  int i = a < c ? a : c;
  int j = a < c ? c : a;
  return ((i*(255 - i))>>1) + (j - i - 1);
}

// ---- canonical fp32 workspace layout (float offsets). edge_feat NOT converted. ----
#define C_NODE 0LL
#define C_MASK 262144LL
#define C_WQKV 327168LL
#define C_BQKV 523776LL
#define C_WEV  524544LL
#define C_BEV  557312LL
#define C_WEA  557568LL
#define C_BEA  558592LL
#define C_WO   558600LL
#define C_BO   689672LL
#define C_WSK  689928LL
#define C_BSK  821000LL
#define C_GN   821512LL
#define C_BN   821768LL
#define C_GE   822024LL
#define C_BE   822152LL
#define IOFF   822400LL
#define TOT8   102785
#define CONVBLKS 402          // ceil(TOT8/256)
// intermediates (float offsets from IOFF)
#define I_NIN  0LL
#define I_Q    262144LL
#define I_K    524288LL
#define I_V    786432LL
#define I_ATTN 1048576LL
#define I_COMB 1310720LL
#define I_EA2  1572864LL   // [B][PP][8] f32 = 520192
#define I_XG   2093056LL   // [BP][128] bf16 = 4161536 float-slots
#define I_WT   14577664LL  // [256][128] bf16 = 16384 float-slots
#define I_WOB  14594048LL  // [512][256] bf16 = 65536 float-slots
#define I_WSKB 14659584LL  // [256][512] bf16 = 65536 float-slots
#define I_FLG  14725120LL

// ---------------- Converter + Wev transpose + Wo/Wsk bf16 + dtype detect ----------
struct SrcPtrs { const void* p[16]; };

__global__ __launch_bounds__(256) void k_convert(SrcPtrs sp, float* __restrict__ dst,
                                                 int* __restrict__ flags,
                                                 const unsigned short* __restrict__ nodeRaw,
                                                 const void* __restrict__ rawWev,
                                                 bf16* __restrict__ Wt,
                                                 const void* __restrict__ rawWo,
                                                 const void* __restrict__ rawWsk,
                                                 bf16* __restrict__ WoB,
                                                 bf16* __restrict__ WskB)
{
  __shared__ int sbad;
  if (threadIdx.x == 0) sbad = 0;
  __syncthreads();
  {
    int bad = 0;
    for (int i = threadIdx.x; i < 1024; i += 256){
      unsigned e = (nodeRaw[i] >> 7) & 0xFFu;
      if (e >= 194u) bad = 1;
    }
    if (bad) sbad = 1;
  }
  __syncthreads();
  const int f32 = sbad;        // 1 = inputs fp32, 0 = bf16
  if (blockIdx.x == 0 && threadIdx.x == 0) flags[0] = f32;

  if (blockIdx.x >= CONVBLKS + 128){
    // Wo / Wsk -> bf16, same [k][n] layout. 32768 octets total.
    int o = (blockIdx.x - (CONVBLKS + 128))*256 + threadIdx.x;   // < 32768
    const void* src = (o < 16384) ? rawWo : rawWsk;
    bf16* dw = (o < 16384) ? WoB : WskB;
    int lo = (o < 16384) ? o : o - 16384;
    if (f32){
      const float4* s4 = (const float4*)src;
      float4 a0 = s4[2*lo], a1 = s4[2*lo+1];
      union { float4 f; bf16 h[8]; } cv;
      cv.h[0]=__float2bfloat16(a0.x); cv.h[1]=__float2bfloat16(a0.y);
      cv.h[2]=__float2bfloat16(a0.z); cv.h[3]=__float2bfloat16(a0.w);
      cv.h[4]=__float2bfloat16(a1.x); cv.h[5]=__float2bfloat16(a1.y);
      cv.h[6]=__float2bfloat16(a1.z); cv.h[7]=__float2bfloat16(a1.w);
      *reinterpret_cast<float4*>(dw + lo*8) = cv.f;
    } else {
      *reinterpret_cast<float4*>(dw + lo*8) = ((const float4*)src)[lo];  // bit-exact copy
    }
    return;
  }

  if (blockIdx.x >= CONVBLKS){
    // Wev transpose from RAW input: idx over [128][256] -> Wt [256][128] bf16
    int idx = (blockIdx.x - CONVBLKS)*256 + threadIdx.x;   // < 32768
    float v = f32 ? ((const float*)rawWev)[idx]
                  : bfraw2f(((const short*)rawWev)[idx]);
    Wt[(idx & 255)*128 + (idx >> 8)] = __float2bfloat16(v);
    return;
  }

  int o = blockIdx.x*256 + threadIdx.x;
  if (o >= TOT8) return;
  const int cum[17] = {0,32768,40896,65472,65568,69664,69696,69824,69825,
                       86209,86241,102625,102689,102721,102753,102769,102785};
  int s = 0;
  #pragma unroll
  for (int i = 1; i <= 15; i++) if (o >= cum[i]) s = i;
  const int li = o - cum[s];
  float4 r0, r1;
  if (f32){
    const float4* src = (const float4*)sp.p[s];
    r0 = src[2*li]; r1 = src[2*li+1];
  } else {
    union { float4 f; unsigned short u[8]; } cv;
    cv.f = ((const float4*)sp.p[s])[li];
    r0.x = __uint_as_float((unsigned)cv.u[0] << 16);
    r0.y = __uint_as_float((unsigned)cv.u[1] << 16);
    r0.z = __uint_as_float((unsigned)cv.u[2] << 16);
    r0.w = __uint_as_float((unsigned)cv.u[3] << 16);
    r1.x = __uint_as_float((unsigned)cv.u[4] << 16);
    r1.y = __uint_as_float((unsigned)cv.u[5] << 16);
    r1.z = __uint_as_float((unsigned)cv.u[6] << 16);
    r1.w = __uint_as_float((unsigned)cv.u[7] << 16);
  }
  float4* d = (float4*)(dst + (long long)cum[s]*8);
  d[2*li]   = r0;
  d[2*li+1] = r1;
}

// ---------------- Kernel 1: node LN + QKV GEMM, column-split x3 ----------------
// grid 768 = 256 rowgroups(4 rows) x 3 outputs {q,k,v}; block 256
// v is stored row-major [b][n][256] (col = h*32+d) for the fused attention kernel.
__global__ __launch_bounds__(256) void k1_node_ln_qkv(
    const float* __restrict__ cnode, const float* __restrict__ cWqkv,
    const float* __restrict__ cbqkv, const float* __restrict__ cgn, const float* __restrict__ cbn,
    float* __restrict__ nin_ws, float* __restrict__ q_ws, float* __restrict__ k_ws,
    float* __restrict__ v_ws)
{
  __shared__ float xln[4][HN];
  const int t = threadIdx.x, wv = t>>6, lane = t&63;
  const int cb = blockIdx.x % 3;           // 0=q, 1=k, 2=v
  const int g0 = (blockIdx.x / 3) * 4;
  {
    int g = g0 + wv;
    float x[4];
    #pragma unroll
    for (int i=0;i<4;i++) x[i] = cnode[g*HN + lane + 64*i];
    float s = x[0]+x[1]+x[2]+x[3];
    s = wave_sum(s);
    float m = s * (1.0f/HN);
    float q = 0.f;
    #pragma unroll
    for (int i=0;i<4;i++){ float d = x[i]-m; q += d*d; }
    q = wave_sum(q);
    float rstd = rsqrtf(fmaxf(q*(1.0f/HN), 0.f) + 1e-5f);
    #pragma unroll
    for (int i=0;i<4;i++){
      int c = lane + 64*i;
      float y = (x[i]-m)*rstd*cgn[c] + cbn[c];
      xln[wv][c] = y;
      if (cb == 0) nin_ws[g*HN + c] = y;
    }
  }
  __syncthreads();
  const int col = cb*256 + t;
  float acc[4];
  {
    float bb = cbqkv[col];
    #pragma unroll
    for (int r=0;r<4;r++) acc[r] = bb;
  }
  for (int k=0;k<HN;k+=4){
    float4 xv[4];
    #pragma unroll
    for (int r=0;r<4;r++) xv[r] = *reinterpret_cast<const float4*>(&xln[r][k]);
    #pragma unroll
    for (int kk=0;kk<4;kk++){
      float w = cWqkv[(k+kk)*768 + col];
      #pragma unroll
      for (int r=0;r<4;r++) acc[r] = fmaf((&xv[r].x)[kk], w, acc[r]);
    }
  }
  if (cb == 2){
    // v: row-major [b][n][256], col = t = h*32+d
    #pragma unroll
    for (int r=0;r<4;r++) v_ws[(long)(g0+r)*HN + t] = acc[r];
  } else {
    float* dstp = (cb == 0) ? q_ws : k_ws;
    const int h = t>>5, d = t&31;
    #pragma unroll
    for (int r=0;r<4;r++){
      int g = g0 + r;
      int b = g>>7, n = g&127;
      dstp[((b*NH + h)*NN + n)*DH + d] = acc[r];
    }
  }
}

// ---------------- k2a: edge LN -> xg (bf16), Wea GEMM + mask fold -> ea2 ----------
// grid 4064 (16 rows/block), block 256
// ea2 layout is [b][p][8] so the attention kernel gathers 32 contiguous bytes/pair.
__global__ __launch_bounds__(256) void k2a_edge_ln(
    const void* __restrict__ edge_raw, const float* __restrict__ cWea,
    const float* __restrict__ cbea, const float* __restrict__ cge,
    const float* __restrict__ cbe, const float* __restrict__ cmask,
    bf16* __restrict__ xg, float* __restrict__ ea2, const int* __restrict__ flags)
{
  __shared__ float xlnS[16][136];
  __shared__ float part[128];
  const int t = threadIdx.x;
  const int R0 = blockIdx.x*16;
  const int b = R0 / PP;
  const int p0 = R0 - b*PP;
  const int f32 = flags[0];
  {
    int r = t>>4, sub = t&15;
    long base = (long)(R0 + r)*HE + sub*8;
    float x[8];
    if (f32){
      const float* cef = (const float*)edge_raw + base;
      float4 a0 = *reinterpret_cast<const float4*>(cef);
      float4 a1 = *reinterpret_cast<const float4*>(cef + 4);
      x[0]=a0.x; x[1]=a0.y; x[2]=a0.z; x[3]=a0.w;
      x[4]=a1.x; x[5]=a1.y; x[6]=a1.z; x[7]=a1.w;
    } else {
      union { float4 f; short u[8]; } cv;
      cv.f = *reinterpret_cast<const float4*>((const bf16*)edge_raw + base);
      #pragma unroll
      for (int i=0;i<8;i++) x[i] = bfraw2f(cv.u[i]);
    }
    float s = 0.f;
    #pragma unroll
    for (int i=0;i<8;i++) s += x[i];
    s = g16_sum(s);
    float m = s*(1.0f/HE);
    float q = 0.f;
    #pragma unroll
    for (int i=0;i<8;i++){ float dd = x[i]-m; q += dd*dd; }
    q = g16_sum(q);
    float rstd = rsqrtf(fmaxf(q*(1.0f/HE), 0.f) + 1e-5f);
    #pragma unroll
    for (int i=0;i<8;i++){
      int c = sub*8 + i;
      xlnS[r][c] = (x[i]-m)*rstd*cge[c] + cbe[c];
    }
  }
  __syncthreads();
  // write xg: thread -> row = t>>4, 8 consecutive cols
  {
    int r = t>>4, c0 = (t&15)*8;
    union { float4 f; bf16 h[8]; } o;
    #pragma unroll
    for (int i=0;i<8;i++) o.h[i] = __float2bfloat16(xlnS[r][c0+i]);
    *reinterpret_cast<float4*>(xg + (long)(R0 + r)*HE + c0) = o.f;
  }
  // e_adj (+mask fold): all 256 threads; (r,c) with k-range split by half
  {
    const int c = t & 7, r = (t>>3) & 15, half = t>>7;
    const int pid = r*8 + c;
    float s = half ? 0.0f : cbea[c];
    const int k0 = half*64;
    #pragma unroll 8
    for (int k=k0; k<k0+64; k++) s = fmaf(xlnS[r][k], cWea[k*NH + c], s);
    if (half){ part[pid] = s; }
    __syncthreads();
    if (!half){
      s += part[pid];
      int p = p0 + r;
      float mk = cmask[b*PP + p];
      ea2[((long)b*PP + p)*8 + c] = (mk != 0.0f) ? s : -9e15f;
    }
  }
}

// ---------------- Kernel 3: fused graph attention, all heads per (b,n) ----------
// attn[b,n,h,:] = sum_m p_hm * v[m] + (sum_m p_hm * xg[pr]) @ Wev_h + (sum p)*bev_h
// e_val is never materialized: the Wev projection commutes past the softmax and
// the xg gather (256B rows) is shared across all 8 heads.
// grid B*N = 1024 blocks (XCD-swizzled so each XCD owns one b); block 256 (32 lanes/head)
__global__ __launch_bounds__(256) void k3_attn(
    const float* __restrict__ q_ws,   // [b][h][n][32]
    const float* __restrict__ k_ws,   // [b][h][n][32]
    const float* __restrict__ v_ws,   // [b][n][256]
    const bf16* __restrict__ xg,      // [b*PP][128]
    const float* __restrict__ ea2,    // [b][PP][8]
    const bf16* __restrict__ Wt,      // [256][128]  (Wev^T)
    const float* __restrict__ cbev,   // [256]
    float* __restrict__ attn)         // [b][n][256]
{
  __shared__ __align__(16) float qS[8][32];
  __shared__ __align__(16) int   prS[128];
  __shared__ __align__(16) float eaS[128][8];
  __shared__ __align__(16) float pS[8][128];
  __shared__ __align__(16) float sS[8][128];
  __shared__ float anyS[8];
  const int t = threadIdx.x;
  const int bid = blockIdx.x;
  const int swz = (bid & 7)*128 + (bid >> 3);   // XCD j owns contiguous swz range = one b
  const int n = swz & 127, b = swz >> 7;
  const int h = t >> 5, ln = t & 31;

  // Phase A: stage q, pair indices, gathered edge-adj logits
  qS[h][ln] = q_ws[(((long)b*NH + h)*NN + n)*DH + ln];
  if (t < 128){
    int m = t;
    prS[m] = pair_idx(n, (m == n) ? (m ^ 1) : m);
  }
  __syncthreads();
  {
    int m = t >> 1, c0 = (t & 1)*4;
    float4 ev = *reinterpret_cast<const float4*>(ea2 + ((long)b*PP + prS[m])*8 + c0);
    *reinterpret_cast<float4*>(&eaS[m][c0]) = ev;
  }
  __syncthreads();

  // Phase B: fp32 QK dots + softmax per head (width-32 shuffle reductions)
  const float scale = 0.17677669529663687f;  // 32^-0.5
  float4 qv[8];
  #pragma unroll
  for (int d4=0; d4<8; d4++) qv[d4] = *reinterpret_cast<const float4*>(&qS[h][d4*4]);
  const float* kb = k_ws + ((long)b*NH + h)*NN*DH;
  float l[4];
  float mx = -INFINITY;
  int valid = 0;
  #pragma unroll
  for (int j=0;j<4;j++){
    int m = ln + 32*j;
    const float* kr = kb + m*DH;
    float dot = 0.f;
    #pragma unroll
    for (int d4=0; d4<8; d4++){
      float4 kv = *reinterpret_cast<const float4*>(kr + d4*4);
      dot = fmaf((&qv[d4].x)[0], kv.x, dot);
      dot = fmaf((&qv[d4].x)[1], kv.y, dot);
      dot = fmaf((&qv[d4].x)[2], kv.z, dot);
      dot = fmaf((&qv[d4].x)[3], kv.w, dot);
    }
    float eav = eaS[m][h];
    bool self = (m == n);
    l[j] = self ? -INFINITY : fmaf(dot, scale, eav);
    if (!self && eav > -8.9e15f) valid = 1;
    mx = fmaxf(mx, l[j]);
  }
  #pragma unroll
  for (int off=16; off>=1; off>>=1) mx = fmaxf(mx, __shfl_xor(mx, off, 32));
  float e[4], s = 0.f;
  #pragma unroll
  for (int j=0;j<4;j++){ e[j] = __expf(l[j]-mx); s += e[j]; }
  float av = valid ? 1.f : 0.f;
  #pragma unroll
  for (int off=16; off>=1; off>>=1){
    s  += __shfl_xor(s,  off, 32);
    av += __shfl_xor(av, off, 32);
  }
  float inv = (av > 0.f) ? (1.0f/s) : 0.f;
  #pragma unroll
  for (int j=0;j<4;j++) pS[h][ln+32*j] = e[j]*inv;
  if (ln == 0) anyS[h] = (av > 0.f) ? 1.f : 0.f;
  __syncthreads();

  // Phase C: p-weighted gather-accumulate. S = sum p*xg[pr] (128-dim, 4 dims/lane),
  // T = sum p*v. pm is identical across heads -> the p==0 skip is wave-uniform.
  const bf16* xgb = xg + (long)b*PP*HE;
  const float* vb = v_ws + (long)b*NN*HN + h*DH + ln;
  float S0=0.f,S1=0.f,S2=0.f,S3=0.f,T=0.f;
  for (int m0=0; m0<128; m0+=4){
    float4 p4 = *reinterpret_cast<const float4*>(&pS[h][m0]);
    int4  pr4 = *reinterpret_cast<const int4*>(&prS[m0]);
    #pragma unroll
    for (int i=0;i<4;i++){
      float pm = (&p4.x)[i];
      if (pm != 0.f){
        int pr = (&pr4.x)[i];
        short4 xv = *reinterpret_cast<const short4*>(
            reinterpret_cast<const short*>(xgb + (long)pr*HE) + ln*4);
        S0 = fmaf(pm, bfraw2f(xv.x), S0);
        S1 = fmaf(pm, bfraw2f(xv.y), S1);
        S2 = fmaf(pm, bfraw2f(xv.z), S2);
        S3 = fmaf(pm, bfraw2f(xv.w), S3);
        T  = fmaf(pm, vb[(m0+i)*HN], T);
      }
    }
  }
  {
    float4 sv; sv.x=S0; sv.y=S1; sv.z=S2; sv.w=S3;
    *reinterpret_cast<float4*>(&sS[h][ln*4]) = sv;
  }
  __syncthreads();

  // Phase D: per-head 128x32 matvec with Wt (L2-resident), + bev + v-part
  float acc = T + anyS[h]*cbev[h*DH + ln];
  const bf16* wr = Wt + (h*DH + ln)*HE;
  #pragma unroll 4
  for (int k0=0;k0<128;k0+=8){
    float4 sa = *reinterpret_cast<const float4*>(&sS[h][k0]);
    float4 sb = *reinterpret_cast<const float4*>(&sS[h][k0+4]);
    bf16x8 wv = *reinterpret_cast<const bf16x8*>(wr + k0);
    acc = fmaf(sa.x, bfraw2f(wv[0]), acc);
    acc = fmaf(sa.y, bfraw2f(wv[1]), acc);
    acc = fmaf(sa.z, bfraw2f(wv[2]), acc);
    acc = fmaf(sa.w, bfraw2f(wv[3]), acc);
    acc = fmaf(sb.x, bfraw2f(wv[4]), acc);
    acc = fmaf(sb.y, bfraw2f(wv[5]), acc);
    acc = fmaf(sb.z, bfraw2f(wv[6]), acc);
    acc = fmaf(sb.w, bfraw2f(wv[7]), acc);
  }
  attn[((long)b*NN + n)*HN + h*DH + ln] = acc;
}

// ---------------- k4: concat(n_in, attn) @ Wo + bo, GELU ----------------
// grid 1024 = 256 rowgroups(4 rows) x 4 col-quarters(64); block 256 = 64 cols x 4 K-slices
__global__ __launch_bounds__(256) void k4_wo_gelu(
    const float* __restrict__ nin_ws, const float* __restrict__ attn,
    const bf16* __restrict__ WoB, const float* __restrict__ cbo,
    float* __restrict__ comb)
{
  __shared__ float xc[4][512];
  __shared__ float ps[3][4][64];
  const int t = threadIdx.x;
  const int g0 = (blockIdx.x >> 2) * 4;
  const int cq = blockIdx.x & 3;
  {
    int r = t>>6, c0 = (t&63)*8;
    const float* src = (c0 < 256) ? (nin_ws + (long)(g0+r)*HN + c0)
                                  : (attn + (long)(g0+r)*HN + (c0-256));
    float4 a0 = *reinterpret_cast<const float4*>(src);
    float4 a1 = *reinterpret_cast<const float4*>(src+4);
    *reinterpret_cast<float4*>(&xc[r][c0]) = a0;
    *reinterpret_cast<float4*>(&xc[r][c0+4]) = a1;
  }
  __syncthreads();
  const int cidx = t & 63, ks = t >> 6;
  const int col = cq*64 + cidx;
  float acc[4] = {0.f,0.f,0.f,0.f};
  const int k0 = ks*128;
  #pragma unroll 4
  for (int k=k0; k<k0+128; k++){
    float w = bf2f(WoB[k*HN + col]);
    #pragma unroll
    for (int r=0;r<4;r++) acc[r] = fmaf(xc[r][k], w, acc[r]);
  }
  if (ks){
    #pragma unroll
    for (int r=0;r<4;r++) ps[ks-1][r][cidx] = acc[r];
  }
  __syncthreads();
  if (!ks){
    float bb = cbo[col];
    #pragma unroll
    for (int r=0;r<4;r++){
      float x = acc[r] + bb + ps[0][r][cidx] + ps[1][r][cidx] + ps[2][r][cidx];
      comb[(long)(g0+r)*HN + col] = 0.5f*x*(1.0f + erff(x*0.7071067811865475f));
    }
  }
}

// ---------------- k5: comb @ Wsk + bsk, sigmoid gate + residual ----------------
// grid 1024 = 256 rowgroups(4 rows) x 4 col-quarters(64 val-cols); block 256 = 64 x 4 K-slices
__global__ __launch_bounds__(256) void k5_sk_gate(
    const float* __restrict__ comb, const float* __restrict__ cnode,
    const bf16* __restrict__ WskB, const float* __restrict__ cbsk,
    void* __restrict__ out, const int* __restrict__ flags)
{
  __shared__ float xc[4][HN];
  __shared__ float psv[3][4][64];
  __shared__ float psg[3][4][64];
  const int t = threadIdx.x;
  const int g0 = (blockIdx.x >> 2) * 4;
  const int cq = blockIdx.x & 3;
  {
    int r = t>>6, c0 = (t&63)*4;
    *reinterpret_cast<float4*>(&xc[r][c0]) =
        *reinterpret_cast<const float4*>(comb + (long)(g0+r)*HN + c0);
  }
  __syncthreads();
  const int cidx = t & 63, ks = t >> 6;
  const int col = cq*64 + cidx;
  float av[4] = {0.f,0.f,0.f,0.f}, ag[4] = {0.f,0.f,0.f,0.f};
  const int k0 = ks*64;
  #pragma unroll 4
  for (int k=k0; k<k0+64; k++){
    float wv = bf2f(WskB[k*512 + col]);
    float wg = bf2f(WskB[k*512 + col + 256]);
    #pragma unroll
    for (int r=0;r<4;r++){
      float xr = xc[r][k];
      av[r] = fmaf(xr, wv, av[r]);
      ag[r] = fmaf(xr, wg, ag[r]);
    }
  }
  if (ks){
    #pragma unroll
    for (int r=0;r<4;r++){ psv[ks-1][r][cidx] = av[r]; psg[ks-1][r][cidx] = ag[r]; }
  }
  __syncthreads();
  if (!ks){
    const int f32 = flags[0];
    float bv = cbsk[col], bg = cbsk[col+256];
    #pragma unroll
    for (int r=0;r<4;r++){
      float v = av[r] + bv + psv[0][r][cidx] + psv[1][r][cidx] + psv[2][r][cidx];
      float g = ag[r] + bg + psg[0][r][cidx] + psg[1][r][cidx] + psg[2][r][cidx];
      float gg = 1.0f/(1.0f + __expf(-g));
      float nf = cnode[(long)(g0+r)*HN + col];
      float res = nf*(1.0f - gg) + v*gg;
      if (f32) ((float*)out)[(long)(g0+r)*HN + col] = res;
      else ((bf16*)out)[(long)(g0+r)*HN + col] = __float2bfloat16(res);
    }
  }
}

extern "C" void kernel_launch(void* const* d_in, const int* in_sizes, int n_inputs,
                              void* d_out, int out_size, void* d_ws, size_t ws_size,
                              hipStream_t stream)
{
  float* ws = (float*)d_ws;
  float* c_node = ws + C_NODE;
  float* c_mask = ws + C_MASK;
  float* c_Wqkv = ws + C_WQKV;
  float* c_bqkv = ws + C_BQKV;
  float* c_bev  = ws + C_BEV;
  float* c_Wea  = ws + C_WEA;
  float* c_bea  = ws + C_BEA;
  float* c_bo   = ws + C_BO;
  float* c_bsk  = ws + C_BSK;
  float* c_gn   = ws + C_GN;
  float* c_bn   = ws + C_BN;
  float* c_ge   = ws + C_GE;
  float* c_be   = ws + C_BE;
  float* base   = ws + IOFF;
  float* nin_ws  = base + I_NIN;
  float* q_ws    = base + I_Q;
  float* k_ws    = base + I_K;
  float* v_ws    = base + I_V;
  float* attn_ws = base + I_ATTN;
  float* comb_ws = base + I_COMB;
  float* ea2_ws  = base + I_EA2;
  bf16*  xg_ws   = (bf16*)(base + I_XG);
  bf16*  wt_ws   = (bf16*)(base + I_WT);
  bf16*  wob_ws  = (bf16*)(base + I_WOB);
  bf16*  wskb_ws = (bf16*)(base + I_WSKB);
  int*   flags   = (int*)(base + I_FLG);

  SrcPtrs sp;
  sp.p[0]  = d_in[0];   // node_feat
  sp.p[1]  = d_in[4];   // mask_valid
  sp.p[2]  = d_in[5];   // Wqkv
  sp.p[3]  = d_in[6];   // bqkv
  sp.p[4]  = d_in[7];   // Wev
  sp.p[5]  = d_in[8];   // bev
  sp.p[6]  = d_in[9];   // Wea
  sp.p[7]  = d_in[10];  // bea
  sp.p[8]  = d_in[11];  // Wo
  sp.p[9]  = d_in[12];  // bo
  sp.p[10] = d_in[13];  // Wsk
  sp.p[11] = d_in[14];  // bsk
  sp.p[12] = d_in[15];  // gn
  sp.p[13] = d_in[16];  // bn
  sp.p[14] = d_in[17];  // ge
  sp.p[15] = d_in[18];  // be

  k_convert<<<CONVBLKS + 256, 256, 0, stream>>>(sp, ws, flags,
                                                (const unsigned short*)d_in[0],
                                                d_in[7], wt_ws,
                                                d_in[11], d_in[13],
                                                wob_ws, wskb_ws);
  k1_node_ln_qkv<<<768, 256, 0, stream>>>(c_node, c_Wqkv, c_bqkv, c_gn, c_bn,
                                          nin_ws, q_ws, k_ws, v_ws);
  k2a_edge_ln<<<BP/16, 256, 0, stream>>>(d_in[1], c_Wea, c_bea, c_ge, c_be, c_mask,
                                         xg_ws, ea2_ws, flags);
  k3_attn<<<BB*NN, 256, 0, stream>>>(q_ws, k_ws, v_ws, xg_ws, ea2_ws, wt_ws, c_bev,
                                     attn_ws);
  k4_wo_gelu<<<1024, 256, 0, stream>>>(nin_ws, attn_ws, wob_ws, c_bo, comb_ws);
  k5_sk_gate<<<1024, 256, 0, stream>>>(comb_ws, c_node, wskb_ws, c_bsk, d_out, flags);
}

// Round 2
// 197.954 us; speedup vs baseline: 1.2025x; 1.2025x over previous
//
#include <hip/hip_runtime.h>
#include <hip/hip_bf16.h>
#include <math.h>

#define BB 8
#define NN 128
#define HN 256
#define HE 128
#define NH 8
#define DH 32
#define PP 8128
#define BP (BB*PP)   // 65024

typedef __hip_bfloat16 bf16;
typedef __hip_bfloat162 bf162;
typedef __attribute__((ext_vector_type(8))) short bf16x8;
typedef __attribute__((ext_vector_type(4))) float f32x4;

__device__ __forceinline__ float bf2f(bf16 x){ return __bfloat162float(x); }
__device__ __forceinline__ float bfraw2f(short u){
  return __uint_as_float(((unsigned)(unsigned short)u) << 16);
}

__device__ __forceinline__ float wave_sum(float v){
  #pragma unroll
  for (int off=32; off>=1; off>>=1) v += __shfl_xor(v, off, 64);
  return v;
}
__device__ __forceinline__ float g16_sum(float v){
  #pragma unroll
  for (int off=8; off>=1; off>>=1) v += __shfl_xor(v, off, 16);
  return v;
}

// triu pair index for N=128, i<j: p = i*(255-i)/2 + (j-i-1)
__device__ __forceinline__ int pair_idx(int a, int c){
  int i = a < c ? a : c;
  int j = a < c ? c : a;
  return ((i*(255 - i))>>1) + (j - i - 1);
}

// ---- canonical fp32 workspace layout (float offsets). edge_feat NOT converted. ----
#define C_NODE 0LL
#define C_MASK 262144LL
#define C_WQKV 327168LL
#define C_BQKV 523776LL
#define C_WEV  524544LL
#define C_BEV  557312LL
#define C_WEA  557568LL
#define C_BEA  558592LL
#define C_WO   558600LL
#define C_BO   689672LL
#define C_WSK  689928LL
#define C_BSK  821000LL
#define C_GN   821512LL
#define C_BN   821768LL
#define C_GE   822024LL
#define C_BE   822152LL
#define IOFF   822400LL
#define TOT8   102785
#define CONVBLKS 402          // ceil(TOT8/256)
// intermediates (float offsets from IOFF)
#define I_NIN  0LL
#define I_Q    262144LL
#define I_K    524288LL
#define I_V    786432LL
#define I_ATTN 1048576LL
#define I_COMB 1310720LL
#define I_EA2  1572864LL   // [B][PP][8] f32 = 520192
#define I_XG   2093056LL   // [BP][128] bf16 = 4161536 float-slots
#define I_WT   14577664LL  // [256][128] bf16 = 16384 float-slots
#define I_WOB  14594048LL  // [512][256] bf16 = 65536 float-slots
#define I_WSKB 14659584LL  // [256][512] bf16 = 65536 float-slots
#define I_FLG  14725120LL

// ---------------- Converter + Wev transpose + Wo/Wsk bf16 + dtype detect ----------
struct SrcPtrs { const void* p[16]; };

__global__ __launch_bounds__(256) void k_convert(SrcPtrs sp, float* __restrict__ dst,
                                                 int* __restrict__ flags,
                                                 const unsigned short* __restrict__ nodeRaw,
                                                 const void* __restrict__ rawWev,
                                                 bf16* __restrict__ Wt,
                                                 const void* __restrict__ rawWo,
                                                 const void* __restrict__ rawWsk,
                                                 bf16* __restrict__ WoB,
                                                 bf16* __restrict__ WskB)
{
  __shared__ int sbad;
  if (threadIdx.x == 0) sbad = 0;
  __syncthreads();
  {
    int bad = 0;
    for (int i = threadIdx.x; i < 1024; i += 256){
      unsigned e = (nodeRaw[i] >> 7) & 0xFFu;
      if (e >= 194u) bad = 1;
    }
    if (bad) sbad = 1;
  }
  __syncthreads();
  const int f32 = sbad;        // 1 = inputs fp32, 0 = bf16
  if (blockIdx.x == 0 && threadIdx.x == 0) flags[0] = f32;

  if (blockIdx.x >= CONVBLKS + 128){
    // Wo / Wsk -> bf16, same [k][n] layout. 32768 octets total.
    int o = (blockIdx.x - (CONVBLKS + 128))*256 + threadIdx.x;   // < 32768
    const void* src = (o < 16384) ? rawWo : rawWsk;
    bf16* dw = (o < 16384) ? WoB : WskB;
    int lo = (o < 16384) ? o : o - 16384;
    if (f32){
      const float4* s4 = (const float4*)src;
      float4 a0 = s4[2*lo], a1 = s4[2*lo+1];
      union { float4 f; bf16 h[8]; } cv;
      cv.h[0]=__float2bfloat16(a0.x); cv.h[1]=__float2bfloat16(a0.y);
      cv.h[2]=__float2bfloat16(a0.z); cv.h[3]=__float2bfloat16(a0.w);
      cv.h[4]=__float2bfloat16(a1.x); cv.h[5]=__float2bfloat16(a1.y);
      cv.h[6]=__float2bfloat16(a1.z); cv.h[7]=__float2bfloat16(a1.w);
      *reinterpret_cast<float4*>(dw + lo*8) = cv.f;
    } else {
      *reinterpret_cast<float4*>(dw + lo*8) = ((const float4*)src)[lo];  // bit-exact copy
    }
    return;
  }

  if (blockIdx.x >= CONVBLKS){
    // Wev transpose from RAW input: idx over [128][256] -> Wt [256][128] bf16
    int idx = (blockIdx.x - CONVBLKS)*256 + threadIdx.x;   // < 32768
    float v = f32 ? ((const float*)rawWev)[idx]
                  : bfraw2f(((const short*)rawWev)[idx]);
    Wt[(idx & 255)*128 + (idx >> 8)] = __float2bfloat16(v);
    return;
  }

  int o = blockIdx.x*256 + threadIdx.x;
  if (o >= TOT8) return;
  const int cum[17] = {0,32768,40896,65472,65568,69664,69696,69824,69825,
                       86209,86241,102625,102689,102721,102753,102769,102785};
  int s = 0;
  #pragma unroll
  for (int i = 1; i <= 15; i++) if (o >= cum[i]) s = i;
  const int li = o - cum[s];
  float4 r0, r1;
  if (f32){
    const float4* src = (const float4*)sp.p[s];
    r0 = src[2*li]; r1 = src[2*li+1];
  } else {
    union { float4 f; unsigned short u[8]; } cv;
    cv.f = ((const float4*)sp.p[s])[li];
    r0.x = __uint_as_float((unsigned)cv.u[0] << 16);
    r0.y = __uint_as_float((unsigned)cv.u[1] << 16);
    r0.z = __uint_as_float((unsigned)cv.u[2] << 16);
    r0.w = __uint_as_float((unsigned)cv.u[3] << 16);
    r1.x = __uint_as_float((unsigned)cv.u[4] << 16);
    r1.y = __uint_as_float((unsigned)cv.u[5] << 16);
    r1.z = __uint_as_float((unsigned)cv.u[6] << 16);
    r1.w = __uint_as_float((unsigned)cv.u[7] << 16);
  }
  float4* d = (float4*)(dst + (long long)cum[s]*8);
  d[2*li]   = r0;
  d[2*li+1] = r1;
}

// ---------------- Kernel 1: node LN + QKV GEMM, column-split x3 ----------------
// grid 768 = 256 rowgroups(4 rows) x 3 outputs {q,k,v}; block 256
// v is stored row-major [b][n][256] (col = h*32+d) for the fused attention kernel.
__global__ __launch_bounds__(256) void k1_node_ln_qkv(
    const float* __restrict__ cnode, const float* __restrict__ cWqkv,
    const float* __restrict__ cbqkv, const float* __restrict__ cgn, const float* __restrict__ cbn,
    float* __restrict__ nin_ws, float* __restrict__ q_ws, float* __restrict__ k_ws,
    float* __restrict__ v_ws)
{
  __shared__ float xln[4][HN];
  const int t = threadIdx.x, wv = t>>6, lane = t&63;
  const int cb = blockIdx.x % 3;           // 0=q, 1=k, 2=v
  const int g0 = (blockIdx.x / 3) * 4;
  {
    int g = g0 + wv;
    float x[4];
    #pragma unroll
    for (int i=0;i<4;i++) x[i] = cnode[g*HN + lane + 64*i];
    float s = x[0]+x[1]+x[2]+x[3];
    s = wave_sum(s);
    float m = s * (1.0f/HN);
    float q = 0.f;
    #pragma unroll
    for (int i=0;i<4;i++){ float d = x[i]-m; q += d*d; }
    q = wave_sum(q);
    float rstd = rsqrtf(fmaxf(q*(1.0f/HN), 0.f) + 1e-5f);
    #pragma unroll
    for (int i=0;i<4;i++){
      int c = lane + 64*i;
      float y = (x[i]-m)*rstd*cgn[c] + cbn[c];
      xln[wv][c] = y;
      if (cb == 0) nin_ws[g*HN + c] = y;
    }
  }
  __syncthreads();
  const int col = cb*256 + t;
  float acc[4];
  {
    float bb = cbqkv[col];
    #pragma unroll
    for (int r=0;r<4;r++) acc[r] = bb;
  }
  for (int k=0;k<HN;k+=4){
    float4 xv[4];
    #pragma unroll
    for (int r=0;r<4;r++) xv[r] = *reinterpret_cast<const float4*>(&xln[r][k]);
    #pragma unroll
    for (int kk=0;kk<4;kk++){
      float w = cWqkv[(k+kk)*768 + col];
      #pragma unroll
      for (int r=0;r<4;r++) acc[r] = fmaf((&xv[r].x)[kk], w, acc[r]);
    }
  }
  if (cb == 2){
    // v: row-major [b][n][256], col = t = h*32+d
    #pragma unroll
    for (int r=0;r<4;r++) v_ws[(long)(g0+r)*HN + t] = acc[r];
  } else {
    float* dstp = (cb == 0) ? q_ws : k_ws;
    const int h = t>>5, d = t&31;
    #pragma unroll
    for (int r=0;r<4;r++){
      int g = g0 + r;
      int b = g>>7, n = g&127;
      dstp[((b*NH + h)*NN + n)*DH + d] = acc[r];
    }
  }
}

// ---------------- k2a: edge LN -> xg (bf16), Wea GEMM + mask fold -> ea2 ----------
// grid 4064 (16 rows/block), block 256
// ea2 layout is [b][p][8] so the attention kernel gathers 32 contiguous bytes/pair.
__global__ __launch_bounds__(256) void k2a_edge_ln(
    const void* __restrict__ edge_raw, const float* __restrict__ cWea,
    const float* __restrict__ cbea, const float* __restrict__ cge,
    const float* __restrict__ cbe, const float* __restrict__ cmask,
    bf16* __restrict__ xg, float* __restrict__ ea2, const int* __restrict__ flags)
{
  __shared__ float xlnS[16][136];
  __shared__ float part[128];
  const int t = threadIdx.x;
  const int R0 = blockIdx.x*16;
  const int b = R0 / PP;
  const int p0 = R0 - b*PP;
  const int f32 = flags[0];
  {
    int r = t>>4, sub = t&15;
    long base = (long)(R0 + r)*HE + sub*8;
    float x[8];
    if (f32){
      const float* cef = (const float*)edge_raw + base;
      float4 a0 = *reinterpret_cast<const float4*>(cef);
      float4 a1 = *reinterpret_cast<const float4*>(cef + 4);
      x[0]=a0.x; x[1]=a0.y; x[2]=a0.z; x[3]=a0.w;
      x[4]=a1.x; x[5]=a1.y; x[6]=a1.z; x[7]=a1.w;
    } else {
      union { float4 f; short u[8]; } cv;
      cv.f = *reinterpret_cast<const float4*>((const bf16*)edge_raw + base);
      #pragma unroll
      for (int i=0;i<8;i++) x[i] = bfraw2f(cv.u[i]);
    }
    float s = 0.f;
    #pragma unroll
    for (int i=0;i<8;i++) s += x[i];
    s = g16_sum(s);
    float m = s*(1.0f/HE);
    float q = 0.f;
    #pragma unroll
    for (int i=0;i<8;i++){ float dd = x[i]-m; q += dd*dd; }
    q = g16_sum(q);
    float rstd = rsqrtf(fmaxf(q*(1.0f/HE), 0.f) + 1e-5f);
    #pragma unroll
    for (int i=0;i<8;i++){
      int c = sub*8 + i;
      xlnS[r][c] = (x[i]-m)*rstd*cge[c] + cbe[c];
    }
  }
  __syncthreads();
  // write xg: thread -> row = t>>4, 8 consecutive cols
  {
    int r = t>>4, c0 = (t&15)*8;
    union { float4 f; bf16 h[8]; } o;
    #pragma unroll
    for (int i=0;i<8;i++) o.h[i] = __float2bfloat16(xlnS[r][c0+i]);
    *reinterpret_cast<float4*>(xg + (long)(R0 + r)*HE + c0) = o.f;
  }
  // e_adj (+mask fold): all 256 threads; (r,c) with k-range split by half
  {
    const int c = t & 7, r = (t>>3) & 15, half = t>>7;
    const int pid = r*8 + c;
    float s = half ? 0.0f : cbea[c];
    const int k0 = half*64;
    #pragma unroll 8
    for (int k=k0; k<k0+64; k++) s = fmaf(xlnS[r][k], cWea[k*NH + c], s);
    if (half){ part[pid] = s; }
    __syncthreads();
    if (!half){
      s += part[pid];
      int p = p0 + r;
      float mk = cmask[b*PP + p];
      ea2[((long)b*PP + p)*8 + c] = (mk != 0.0f) ? s : -9e15f;
    }
  }
}

// ---------------- Kernel 3: fused graph attention, all heads per (b,n) ----------
// attn[b,n,h,:] = sum_m p_hm * v[m] + (sum_m p_hm * xg[pr]) @ Wev_h + (sum p)*bev_h
// e_val never materialized. Gathered xg rows are staged branch-free into LDS
// (32 KB) so the p-weighted accumulate is a pure LDS/VALU pipelined loop;
// the former per-m `if(p!=0)` branch exposed ~200cy L2 latency x128 iters.
// grid B*N = 1024 blocks (XCD-swizzled so each XCD owns one b); block 256 (32 lanes/head)
__global__ __launch_bounds__(256) void k3_attn(
    const float* __restrict__ q_ws,   // [b][h][n][32]
    const float* __restrict__ k_ws,   // [b][h][n][32]
    const float* __restrict__ v_ws,   // [b][n][256]
    const bf16* __restrict__ xg,      // [b*PP][128]
    const float* __restrict__ ea2,    // [b][PP][8]
    const bf16* __restrict__ Wt,      // [256][128]  (Wev^T)
    const float* __restrict__ cbev,   // [256]
    float* __restrict__ attn)         // [b][n][256]
{
  __shared__ __align__(16) float qS[8][32];
  __shared__ __align__(16) int   prS[128];
  __shared__ __align__(16) float eaS[128][8];
  __shared__ __align__(16) float pS[8][128];
  __shared__ __align__(16) float sS[8][128];
  __shared__ __align__(16) bf16  xgS[128][128];   // 32 KB gathered neighbor rows
  __shared__ float anyS[8];
  const int t = threadIdx.x;
  const int bid = blockIdx.x;
  const int swz = (bid & 7)*128 + (bid >> 3);   // XCD j owns contiguous swz range = one b
  const int n = swz & 127, b = swz >> 7;
  const int h = t >> 5, ln = t & 31;

  // Phase A: stage q + pair indices
  qS[h][ln] = q_ws[(((long)b*NH + h)*NN + n)*DH + ln];
  if (t < 128){
    int m = t;
    prS[m] = pair_idx(n, (m == n) ? (m ^ 1) : m);
  }
  __syncthreads();

  // Phase A2: gather edge-adj logits + xg rows into LDS (all branch-free)
  const bf16* xgb = xg + (long)b*PP*HE;
  {
    int m = t >> 1, c0 = (t & 1)*4;
    float4 ev = *reinterpret_cast<const float4*>(ea2 + ((long)b*PP + prS[m])*8 + c0);
    *reinterpret_cast<float4*>(&eaS[m][c0]) = ev;
  }
  #pragma unroll
  for (int it=0; it<8; ++it){
    int idx = it*256 + t;
    int row = idx >> 4, seg = idx & 15;
    int pr = prS[row];
    *reinterpret_cast<float4*>(&xgS[row][seg*8]) =
        *reinterpret_cast<const float4*>(xgb + (long)pr*HE + seg*8);
  }
  __syncthreads();

  // Phase B: fp32 QK dots + softmax per head (width-32 shuffle reductions)
  const float scale = 0.17677669529663687f;  // 32^-0.5
  float4 qv[8];
  #pragma unroll
  for (int d4=0; d4<8; d4++) qv[d4] = *reinterpret_cast<const float4*>(&qS[h][d4*4]);
  const float* kb = k_ws + ((long)b*NH + h)*NN*DH;
  float l[4];
  float mx = -INFINITY;
  int valid = 0;
  #pragma unroll
  for (int j=0;j<4;j++){
    int m = ln + 32*j;
    const float* kr = kb + m*DH;
    float dot = 0.f;
    #pragma unroll
    for (int d4=0; d4<8; d4++){
      float4 kv = *reinterpret_cast<const float4*>(kr + d4*4);
      dot = fmaf((&qv[d4].x)[0], kv.x, dot);
      dot = fmaf((&qv[d4].x)[1], kv.y, dot);
      dot = fmaf((&qv[d4].x)[2], kv.z, dot);
      dot = fmaf((&qv[d4].x)[3], kv.w, dot);
    }
    float eav = eaS[m][h];
    bool self = (m == n);
    l[j] = self ? -INFINITY : fmaf(dot, scale, eav);
    if (!self && eav > -8.9e15f) valid = 1;
    mx = fmaxf(mx, l[j]);
  }
  #pragma unroll
  for (int off=16; off>=1; off>>=1) mx = fmaxf(mx, __shfl_xor(mx, off, 32));
  float e[4], s = 0.f;
  #pragma unroll
  for (int j=0;j<4;j++){ e[j] = __expf(l[j]-mx); s += e[j]; }
  float av = valid ? 1.f : 0.f;
  #pragma unroll
  for (int off=16; off>=1; off>>=1){
    s  += __shfl_xor(s,  off, 32);
    av += __shfl_xor(av, off, 32);
  }
  float inv = (av > 0.f) ? (1.0f/s) : 0.f;
  #pragma unroll
  for (int j=0;j<4;j++) pS[h][ln+32*j] = e[j]*inv;
  if (ln == 0) anyS[h] = (av > 0.f) ? 1.f : 0.f;
  __syncthreads();

  // Phase C: branch-free p-weighted accumulate. S = sum p*xg[pr] (4 dims/lane)
  // from LDS; T = sum p*v from global (coalesced, L2-resident, pipelined).
  const float* vb = v_ws + (long)b*NN*HN + h*DH + ln;
  float S0=0.f,S1=0.f,S2=0.f,S3=0.f,T=0.f;
  #pragma unroll 2
  for (int m0=0; m0<128; m0+=4){
    float4 p4 = *reinterpret_cast<const float4*>(&pS[h][m0]);
    #pragma unroll
    for (int i=0;i<4;i++){
      float pm = (&p4.x)[i];
      short4 xv = *reinterpret_cast<const short4*>(&xgS[m0+i][ln*4]);
      S0 = fmaf(pm, bfraw2f(xv.x), S0);
      S1 = fmaf(pm, bfraw2f(xv.y), S1);
      S2 = fmaf(pm, bfraw2f(xv.z), S2);
      S3 = fmaf(pm, bfraw2f(xv.w), S3);
      T  = fmaf(pm, vb[(m0+i)*HN], T);
    }
  }
  {
    float4 sv; sv.x=S0; sv.y=S1; sv.z=S2; sv.w=S3;
    *reinterpret_cast<float4*>(&sS[h][ln*4]) = sv;
  }
  __syncthreads();

  // Phase D: per-head 128x32 matvec with Wt (L2-resident), + bev + v-part
  float acc = T + anyS[h]*cbev[h*DH + ln];
  const bf16* wr = Wt + (h*DH + ln)*HE;
  #pragma unroll 4
  for (int k0=0;k0<128;k0+=8){
    float4 sa = *reinterpret_cast<const float4*>(&sS[h][k0]);
    float4 sb = *reinterpret_cast<const float4*>(&sS[h][k0+4]);
    bf16x8 wv = *reinterpret_cast<const bf16x8*>(wr + k0);
    acc = fmaf(sa.x, bfraw2f(wv[0]), acc);
    acc = fmaf(sa.y, bfraw2f(wv[1]), acc);
    acc = fmaf(sa.z, bfraw2f(wv[2]), acc);
    acc = fmaf(sa.w, bfraw2f(wv[3]), acc);
    acc = fmaf(sb.x, bfraw2f(wv[4]), acc);
    acc = fmaf(sb.y, bfraw2f(wv[5]), acc);
    acc = fmaf(sb.z, bfraw2f(wv[6]), acc);
    acc = fmaf(sb.w, bfraw2f(wv[7]), acc);
  }
  attn[((long)b*NN + n)*HN + h*DH + ln] = acc;
}

// ---------------- k4: concat(n_in, attn) @ Wo + bo, GELU ----------------
// grid 1024 = 256 rowgroups(4 rows) x 4 col-quarters(64); block 256 = 64 cols x 4 K-slices
__global__ __launch_bounds__(256) void k4_wo_gelu(
    const float* __restrict__ nin_ws, const float* __restrict__ attn,
    const bf16* __restrict__ WoB, const float* __restrict__ cbo,
    float* __restrict__ comb)
{
  __shared__ float xc[4][512];
  __shared__ float ps[3][4][64];
  const int t = threadIdx.x;
  const int g0 = (blockIdx.x >> 2) * 4;
  const int cq = blockIdx.x & 3;
  {
    int r = t>>6, c0 = (t&63)*8;
    const float* src = (c0 < 256) ? (nin_ws + (long)(g0+r)*HN + c0)
                                  : (attn + (long)(g0+r)*HN + (c0-256));
    float4 a0 = *reinterpret_cast<const float4*>(src);
    float4 a1 = *reinterpret_cast<const float4*>(src+4);
    *reinterpret_cast<float4*>(&xc[r][c0]) = a0;
    *reinterpret_cast<float4*>(&xc[r][c0+4]) = a1;
  }
  __syncthreads();
  const int cidx = t & 63, ks = t >> 6;
  const int col = cq*64 + cidx;
  float acc[4] = {0.f,0.f,0.f,0.f};
  const int k0 = ks*128;
  #pragma unroll 4
  for (int k=k0; k<k0+128; k++){
    float w = bf2f(WoB[k*HN + col]);
    #pragma unroll
    for (int r=0;r<4;r++) acc[r] = fmaf(xc[r][k], w, acc[r]);
  }
  if (ks){
    #pragma unroll
    for (int r=0;r<4;r++) ps[ks-1][r][cidx] = acc[r];
  }
  __syncthreads();
  if (!ks){
    float bb = cbo[col];
    #pragma unroll
    for (int r=0;r<4;r++){
      float x = acc[r] + bb + ps[0][r][cidx] + ps[1][r][cidx] + ps[2][r][cidx];
      comb[(long)(g0+r)*HN + col] = 0.5f*x*(1.0f + erff(x*0.7071067811865475f));
    }
  }
}

// ---------------- k5: comb @ Wsk + bsk, sigmoid gate + residual ----------------
// grid 1024 = 256 rowgroups(4 rows) x 4 col-quarters(64 val-cols); block 256 = 64 x 4 K-slices
__global__ __launch_bounds__(256) void k5_sk_gate(
    const float* __restrict__ comb, const float* __restrict__ cnode,
    const bf16* __restrict__ WskB, const float* __restrict__ cbsk,
    void* __restrict__ out, const int* __restrict__ flags)
{
  __shared__ float xc[4][HN];
  __shared__ float psv[3][4][64];
  __shared__ float psg[3][4][64];
  const int t = threadIdx.x;
  const int g0 = (blockIdx.x >> 2) * 4;
  const int cq = blockIdx.x & 3;
  {
    int r = t>>6, c0 = (t&63)*4;
    *reinterpret_cast<float4*>(&xc[r][c0]) =
        *reinterpret_cast<const float4*>(comb + (long)(g0+r)*HN + c0);
  }
  __syncthreads();
  const int cidx = t & 63, ks = t >> 6;
  const int col = cq*64 + cidx;
  float av[4] = {0.f,0.f,0.f,0.f}, ag[4] = {0.f,0.f,0.f,0.f};
  const int k0 = ks*64;
  #pragma unroll 4
  for (int k=k0; k<k0+64; k++){
    float wv = bf2f(WskB[k*512 + col]);
    float wg = bf2f(WskB[k*512 + col + 256]);
    #pragma unroll
    for (int r=0;r<4;r++){
      float xr = xc[r][k];
      av[r] = fmaf(xr, wv, av[r]);
      ag[r] = fmaf(xr, wg, ag[r]);
    }
  }
  if (ks){
    #pragma unroll
    for (int r=0;r<4;r++){ psv[ks-1][r][cidx] = av[r]; psg[ks-1][r][cidx] = ag[r]; }
  }
  __syncthreads();
  if (!ks){
    const int f32 = flags[0];
    float bv = cbsk[col], bg = cbsk[col+256];
    #pragma unroll
    for (int r=0;r<4;r++){
      float v = av[r] + bv + psv[0][r][cidx] + psv[1][r][cidx] + psv[2][r][cidx];
      float g = ag[r] + bg + psg[0][r][cidx] + psg[1][r][cidx] + psg[2][r][cidx];
      float gg = 1.0f/(1.0f + __expf(-g));
      float nf = cnode[(long)(g0+r)*HN + col];
      float res = nf*(1.0f - gg) + v*gg;
      if (f32) ((float*)out)[(long)(g0+r)*HN + col] = res;
      else ((bf16*)out)[(long)(g0+r)*HN + col] = __float2bfloat16(res);
    }
  }
}

extern "C" void kernel_launch(void* const* d_in, const int* in_sizes, int n_inputs,
                              void* d_out, int out_size, void* d_ws, size_t ws_size,
                              hipStream_t stream)
{
  float* ws = (float*)d_ws;
  float* c_node = ws + C_NODE;
  float* c_mask = ws + C_MASK;
  float* c_Wqkv = ws + C_WQKV;
  float* c_bqkv = ws + C_BQKV;
  float* c_bev  = ws + C_BEV;
  float* c_Wea  = ws + C_WEA;
  float* c_bea  = ws + C_BEA;
  float* c_bo   = ws + C_BO;
  float* c_bsk  = ws + C_BSK;
  float* c_gn   = ws + C_GN;
  float* c_bn   = ws + C_BN;
  float* c_ge   = ws + C_GE;
  float* c_be   = ws + C_BE;
  float* base   = ws + IOFF;
  float* nin_ws  = base + I_NIN;
  float* q_ws    = base + I_Q;
  float* k_ws    = base + I_K;
  float* v_ws    = base + I_V;
  float* attn_ws = base + I_ATTN;
  float* comb_ws = base + I_COMB;
  float* ea2_ws  = base + I_EA2;
  bf16*  xg_ws   = (bf16*)(base + I_XG);
  bf16*  wt_ws   = (bf16*)(base + I_WT);
  bf16*  wob_ws  = (bf16*)(base + I_WOB);
  bf16*  wskb_ws = (bf16*)(base + I_WSKB);
  int*   flags   = (int*)(base + I_FLG);

  SrcPtrs sp;
  sp.p[0]  = d_in[0];   // node_feat
  sp.p[1]  = d_in[4];   // mask_valid
  sp.p[2]  = d_in[5];   // Wqkv
  sp.p[3]  = d_in[6];   // bqkv
  sp.p[4]  = d_in[7];   // Wev
  sp.p[5]  = d_in[8];   // bev
  sp.p[6]  = d_in[9];   // Wea
  sp.p[7]  = d_in[10];  // bea
  sp.p[8]  = d_in[11];  // Wo
  sp.p[9]  = d_in[12];  // bo
  sp.p[10] = d_in[13];  // Wsk
  sp.p[11] = d_in[14];  // bsk
  sp.p[12] = d_in[15];  // gn
  sp.p[13] = d_in[16];  // bn
  sp.p[14] = d_in[17];  // ge
  sp.p[15] = d_in[18];  // be

  k_convert<<<CONVBLKS + 256, 256, 0, stream>>>(sp, ws, flags,
                                                (const unsigned short*)d_in[0],
                                                d_in[7], wt_ws,
                                                d_in[11], d_in[13],
                                                wob_ws, wskb_ws);
  k1_node_ln_qkv<<<768, 256, 0, stream>>>(c_node, c_Wqkv, c_bqkv, c_gn, c_bn,
                                          nin_ws, q_ws, k_ws, v_ws);
  k2a_edge_ln<<<BP/16, 256, 0, stream>>>(d_in[1], c_Wea, c_bea, c_ge, c_be, c_mask,
                                         xg_ws, ea2_ws, flags);
  k3_attn<<<BB*NN, 256, 0, stream>>>(q_ws, k_ws, v_ws, xg_ws, ea2_ws, wt_ws, c_bev,
                                     attn_ws);
  k4_wo_gelu<<<1024, 256, 0, stream>>>(nin_ws, attn_ws, wob_ws, c_bo, comb_ws);
  k5_sk_gate<<<1024, 256, 0, stream>>>(comb_ws, c_node, wskb_ws, c_bsk, d_out, flags);
}